// Round 8
// baseline (155.949 us; speedup 1.0000x reference)
//
#include <hip/hip_runtime.h>
#include <cstdint>
#include <cstddef>

// Problem: B=8, C=64, H=W=32 -> N=8192 nodes, K=9 neighbors, OUT=64.
// Batches: k = [1024k,1024(k+1)) for k<=6, batch 7 = [7168,8190], batch 8 = {8191}.
// Node g: b = g>>10, hw = g&1023; feature ch of g = x[b*65536 + ch*1024 + hw].
//
// R8 (= R7 + ILP for the 1-wave/SIMD regime):
//  - phase 1: prefetch 2 channels ahead (pair ping-pong) -> L2 latency covered
//    by ~620 cyc of FMA issue; single barrier (no periodic syncs).
//  - phase 2: all 8 rows' tournaments interleaved (independent rounds) ->
//    ds_bpermute latency overlapped 8-wide; winner-index via second
//    interleaved min-butterfly (branch-free exact tie-break).
//  - phase 3: unchanged.

#define CBUF_STRIDE 1028             // ushorts per channel row (8B-aligned, 4-way-max banks)
#define CBUF_BYTES (64 * CBUF_STRIDE * 2)   // 131,584 B dynamic LDS

__device__ __forceinline__ unsigned mono32(float d) {
  unsigned u = __float_as_uint(d);
  return (u & 0x80000000u) ? ~u : (u | 0x80000000u);
}

__device__ __forceinline__ float rdlane(float v, int src) {
  return __int_as_float(__builtin_amdgcn_readlane(__float_as_int(v), src));
}

__device__ __forceinline__ unsigned short bf16rn(float v) {
  unsigned bits = __float_as_uint(v);
  return (unsigned short)((bits + 0x7FFFu + ((bits >> 16) & 1u)) >> 16);
}

extern "C" __global__ __launch_bounds__(256, 1)
void k_fused(const float* __restrict__ x,
             const float* __restrict__ Wl,
             const float* __restrict__ bl,
             const float* __restrict__ Wr,
             float* __restrict__ out) {
  extern __shared__ unsigned short cbuf[];   // [64][CBUF_STRIDE] bf16
  int t = threadIdx.x;
  int lane = t & 63;
  int w = t >> 6;
  int n0 = (int)blockIdx.x << 5;             // 32 rows per block
  int s = (n0 >= 7168) ? 7168 : (n0 & ~1023);
  const float* xb = x + ((size_t)(s >> 10) << 16);

  // self features: lane = channel
  float rowf[8];
#pragma unroll
  for (int r = 0; r < 8; ++r) {
    int n = n0 + (w << 3) + r;
    rowf[r] = xb[(lane << 10) + (n & 1023)];
  }

  float acc[8][16];
#pragma unroll
  for (int r = 0; r < 8; ++r)
#pragma unroll
    for (int q = 0; q < 16; ++q) acc[r][q] = 0.f;
  float sqc[16];
#pragma unroll
  for (int q = 0; q < 16; ++q) sqc[q] = 0.f;

  // -------- phase 1: channel stream, pair ping-pong (depth-2 prefetch) -----
  float4 pb[2][2][4];                        // [ping][h][e]
#pragma unroll
  for (int h = 0; h < 2; ++h)
#pragma unroll
    for (int e = 0; e < 4; ++e)
      pb[0][h][e] = *(const float4*)&xb[(h << 10) + (lane << 2) + (e << 8)];

#pragma unroll 1
  for (int ch2 = 0; ch2 < 32; ++ch2) {
    int cur = ch2 & 1;
    if (ch2 < 31) {
      int chn = (ch2 << 1) + 2;
#pragma unroll
      for (int h = 0; h < 2; ++h)
#pragma unroll
        for (int e = 0; e < 4; ++e)
          pb[cur ^ 1][h][e] =
              *(const float4*)&xb[((chn + h) << 10) + (lane << 2) + (e << 8)];
    }
#pragma unroll
    for (int h = 0; h < 2; ++h) {
      int ch = (ch2 << 1) + h;
      if ((ch >> 4) == w) {                  // bf16 side-copy: wave w owns 16 ch
#pragma unroll
        for (int e = 0; e < 4; ++e) {
          ushort4 pk;
          pk.x = bf16rn(pb[cur][h][e].x);
          pk.y = bf16rn(pb[cur][h][e].y);
          pk.z = bf16rn(pb[cur][h][e].z);
          pk.w = bf16rn(pb[cur][h][e].w);
          *(ushort4*)&cbuf[ch * CBUF_STRIDE + (lane << 2) + (e << 8)] = pk;
        }
      }
      float rv[8];
#pragma unroll
      for (int r = 0; r < 8; ++r) rv[r] = rdlane(rowf[r], ch);
#pragma unroll
      for (int e = 0; e < 4; ++e) {
        float cv[4] = {pb[cur][h][e].x, pb[cur][h][e].y, pb[cur][h][e].z, pb[cur][h][e].w};
#pragma unroll
        for (int j = 0; j < 4; ++j) {
          int q = (e << 2) + j;
          sqc[q] = fmaf(cv[j], cv[j], sqc[q]);
#pragma unroll
          for (int r = 0; r < 8; ++r)
            acc[r][q] = fmaf(rv[r], cv[j], acc[r][q]);
        }
      }
    }
  }
  __syncthreads();                           // cbuf complete

  // -------- phase 2: 8 interleaved top-9 tournaments + bf16 mean -----------
  float sqr[8];
#pragma unroll
  for (int r = 0; r < 8; ++r) {
    int lr = (n0 + (w << 3) + r) - s;
    int lslot = ((lr >> 8) << 2) | (lr & 3);
    int llane = (lr >> 2) & 63;
    float sel = sqc[0];
#pragma unroll
    for (int q = 1; q < 16; ++q) sel = (q == lslot) ? sqc[q] : sel;
    sqr[r] = __shfl(sel, llane, 64);
  }

  bool mrow = (s == 7168);                   // exclude cand 1023 (node 8191)
  unsigned du[8][16];
#pragma unroll
  for (int r = 0; r < 8; ++r)
#pragma unroll
    for (int q = 0; q < 16; ++q)
      du[r][q] = mono32((sqr[r] + sqc[q]) - 2.f * acc[r][q]);
  if (mrow && lane == 63)
#pragma unroll
    for (int r = 0; r < 8; ++r) du[r][15] = 0xFFFFFFFFu;

  // per-lane cached top-2, all rows
  unsigned m1d[8], m2d[8];
  int m1s[8], m2s[8];
#pragma unroll
  for (int r = 0; r < 8; ++r) {
    unsigned a = du[r][0], b = du[r][1];
    if (b < a) { m1d[r] = b; m2d[r] = a; m1s[r] = 1; m2s[r] = 0; }
    else       { m1d[r] = a; m2d[r] = b; m1s[r] = 0; m2s[r] = 1; }
#pragma unroll
    for (int q = 2; q < 16; ++q) {
      unsigned dq = du[r][q];
      bool lt1 = dq < m1d[r], lt2 = dq < m2d[r];
      m2d[r] = lt1 ? m1d[r] : (lt2 ? dq : m2d[r]);
      m2s[r] = lt1 ? m1s[r] : (lt2 ? q : m2s[r]);
      m1d[r] = lt1 ? dq : m1d[r];
      m1s[r] = lt1 ? q : m1s[r];
    }
  }

  unsigned lmd[8], rmask[8];
  int lms[8];
  unsigned staleM = 0;
  float msum[8];
#pragma unroll
  for (int r = 0; r < 8; ++r) {
    lmd[r] = m1d[r]; lms[r] = m1s[r]; rmask[r] = 0u; msum[r] = 0.f;
  }

#pragma unroll 1
  for (int kk = 0; kk < 9; ++kk) {
    // interleaved dist-min butterfly (8 independent chains)
    unsigned g[8];
#pragma unroll
    for (int r = 0; r < 8; ++r) g[r] = lmd[r];
#pragma unroll
    for (int off = 32; off; off >>= 1) {
#pragma unroll
      for (int r = 0; r < 8; ++r) {
        unsigned o = (unsigned)__shfl_xor((int)g[r], off, 64);
        g[r] = (o < g[r]) ? o : g[r];
      }
    }
    // interleaved index-min butterfly over tying lanes (exact tie-break)
    unsigned wc[8];
#pragma unroll
    for (int r = 0; r < 8; ++r) {
      unsigned cc = ((unsigned)lane << 2) | ((unsigned)(lms[r] >> 2) << 8) |
                    (unsigned)(lms[r] & 3);
      wc[r] = (lmd[r] == g[r]) ? cc : 0xFFFFFFFFu;
    }
#pragma unroll
    for (int off = 32; off; off >>= 1) {
#pragma unroll
      for (int r = 0; r < 8; ++r) {
        unsigned o = (unsigned)__shfl_xor((int)wc[r], off, 64);
        wc[r] = (o < wc[r]) ? o : wc[r];
      }
    }
    // accumulate winners' features (lane = channel) from bf16 LDS
#pragma unroll
    for (int r = 0; r < 8; ++r)
      msum[r] += __uint_as_float(
          (unsigned)cbuf[lane * CBUF_STRIDE + (int)(wc[r] & 1023u)] << 16);
    // state update; rare rescan when a lane's top-2 is exhausted
#pragma unroll
    for (int r = 0; r < 8; ++r) {
      unsigned cc = ((unsigned)lane << 2) | ((unsigned)(lms[r] >> 2) << 8) |
                    (unsigned)(lms[r] & 3);
      if (lmd[r] == g[r] && cc == wc[r]) {   // this lane consumed its min
        rmask[r] |= 1u << lms[r];
        if (!((staleM >> r) & 1u)) {
          lmd[r] = m2d[r]; lms[r] = m2s[r]; staleM |= 1u << r;
        } else {
          unsigned bd = 0xFFFFFFFFu; int bs = 0;
#pragma unroll
          for (int q = 0; q < 16; ++q) {
            bool alive = ((rmask[r] >> q) & 1u) == 0u;
            bool take = alive && (du[r][q] < bd);
            bd = take ? du[r][q] : bd;
            bs = take ? q : bs;
          }
          lmd[r] = bd; lms[r] = bs;
        }
      }
    }
  }

  float ms[8];
#pragma unroll
  for (int r = 0; r < 8; ++r) {
    int n = n0 + (w << 3) + r;
    ms[r] = (n == 8191) ? rowf[r] : msum[r] / 9.0f;   // singleton batch: self
  }

  // -------- phase 3: out = mean@Wl^T + bl + self@Wr^T (lane = out ch) ------
  float4 wl4[16], wr4[16];
#pragma unroll
  for (int k = 0; k < 16; ++k) {
    wl4[k] = *(const float4*)&Wl[(lane << 6) + (k << 2)];
    wr4[k] = *(const float4*)&Wr[(lane << 6) + (k << 2)];
  }
  float bias = bl[lane];
#pragma unroll 1
  for (int r = 0; r < 8; ++r) {
    int n = n0 + (w << 3) + r;
    float accL = 0.f, accR = 0.f;
#pragma unroll
    for (int c = 0; c < 64; ++c) {
      float mc = rdlane(ms[r], c);
      float xc = rdlane(rowf[r], c);
      const float* wlp = (const float*)&wl4[c >> 2];
      const float* wrp = (const float*)&wr4[c >> 2];
      accL = fmaf(mc, wlp[c & 3], accL);
      accR = fmaf(xc, wrp[c & 3], accR);
    }
    out[((size_t)n << 6) + lane] = accL + accR + bias;
  }
}

// ---------------------------------------------------------------------------
extern "C" void kernel_launch(void* const* d_in, const int* in_sizes, int n_in,
                              void* d_out, int out_size, void* d_ws, size_t ws_size,
                              hipStream_t stream) {
  const float* x  = (const float*)d_in[0];   // (8,64,32,32)
  const float* Wl = (const float*)d_in[1];   // (64,64)
  const float* bl = (const float*)d_in[2];   // (64,)
  const float* Wr = (const float*)d_in[3];   // (64,64)
  float* out = (float*)d_out;                // (8192,64)

  // dynamic LDS > 64 KB: opt in every call (idempotent, capture-safe)
  hipFuncSetAttribute((const void*)k_fused,
                      hipFuncAttributeMaxDynamicSharedMemorySize, CBUF_BYTES);
  k_fused<<<256, 256, CBUF_BYTES, stream>>>(x, Wl, bl, Wr, out);
}